// Round 12
// baseline (64.974 us; speedup 1.0000x reference)
//
#include <hip/hip_runtime.h>
#include <hip/hip_bf16.h>
#include <hip/hip_fp16.h>
#include <stdint.h>

#define B_ROWS 2048
#define FEAT   2048
#define NK     128
#define ND     16
#define NCOL   2048   // NK*ND

#define BM 128
#define BN 128
#define BK 32

typedef __attribute__((ext_vector_type(4))) float    f32x4;
typedef __attribute__((ext_vector_type(8)))  _Float16 f16x8;
typedef __attribute__((ext_vector_type(4)))  _Float16 f16x4;
typedef __attribute__((ext_vector_type(2)))  _Float16 f16x2;

__device__ __forceinline__ f16x2 u2h(unsigned u) { return __builtin_bit_cast(f16x2, u); }
__device__ __forceinline__ f16x2 absdiff2(f16x2 a, f16x2 b) {
    f16x2 d = a - b;                       // v_pk_sub_f16
    unsigned u = __builtin_bit_cast(unsigned, d) & 0x7fff7fffu;  // v_and_b32 (abs both halves)
    return __builtin_bit_cast(f16x2, u);
}

// ------------- Kernel 1: fused x-convert + W-transpose/convert (f16) ------
__global__ __launch_bounds__(256) void k_prep(const float* __restrict__ x,
                                              const float* __restrict__ W,
                                              _Float16* __restrict__ x_h,
                                              _Float16* __restrict__ Wt) {
    __shared__ float tile[32][33];
    int bb = blockIdx.x;
    if (bb < 4096) {
        int i = bb * 256 + threadIdx.x;
        float4 v = ((const float4*)x)[i];
        f16x4 o = { (_Float16)v.x, (_Float16)v.y, (_Float16)v.z, (_Float16)v.w };
        *(f16x4*)&x_h[(size_t)i * 4] = o;
    } else {
        bb -= 4096;
        int tid = threadIdx.x;
        int tx = tid & 31, ty = tid >> 5;   // 32 x 8
        int n0 = (bb & 63) * 32, k0 = (bb >> 6) * 32;
        #pragma unroll
        for (int i = 0; i < 4; ++i)
            tile[ty + i * 8][tx] = W[(size_t)(k0 + ty + i * 8) * NCOL + n0 + tx];
        __syncthreads();
        #pragma unroll
        for (int i = 0; i < 4; ++i)
            Wt[(size_t)(n0 + ty + i * 8) * FEAT + k0 + tx] = (_Float16)tile[tx][ty + i * 8];
    }
}

// ---------------- Kernel 2: f16 MFMA GEMM, BK=32, 2-phase dbuf ------------
// LDS 32KB/block -> 4-5 blocks/CU (vs 2 at BK=64): independent blocks hide
// each other's barrier-drain stalls. ds_read bank conflicts removed via
// slot-swizzle p = k_slot ^ ((row>>1)&3), applied as pre-swizzled GLOBAL
// source (LDS stays linear for global_load_lds, m173 pattern) + same XOR
// on the read side. Both sides' XOR terms are per-lane constants (hoisted).
__global__ __launch_bounds__(256) void k_gemm(const _Float16* __restrict__ A,
                                              const _Float16* __restrict__ Bt,
                                              _Float16* __restrict__ Cparts,
                                              int kt_per) {
    __shared__ __align__(16) unsigned short As[2][BM * BK];  // 2 x 8KB
    __shared__ __align__(16) unsigned short Bs[2][BN * BK];  // 2 x 8KB
    const int tid  = threadIdx.x;
    const int wave = tid >> 6;
    const int lane = tid & 63;
    const int bm = blockIdx.y, bn = blockIdx.x, z = blockIdx.z;
    _Float16* C = Cparts + (size_t)z * B_ROWS * NCOL;
    const int wm = (wave >> 1) * 64;
    const int wn = (wave & 1) * 64;

    // Staging: chunk c covers rows c*64 + wave*16 + (lane>>2); global col
    // slot s = (lane&3) ^ ((lane>>3)&3) (pre-swizzled source); LDS linear.
    const int srow4 = lane >> 2;                              // 0..15
    const int scol  = ((lane & 3) ^ ((lane >> 3) & 3)) * 8;   // swizzled k-slot
    const _Float16* gA0 = A  + (size_t)(bm * BM + wave * 16 + srow4) * FEAT + scol;
    const _Float16* gB0 = Bt + (size_t)(bn * BN + wave * 16 + srow4) * FEAT + scol;

    f32x4 acc[4][4];
    #pragma unroll
    for (int i = 0; i < 4; ++i)
        #pragma unroll
        for (int j = 0; j < 4; ++j)
            acc[i][j] = (f32x4){0.f, 0.f, 0.f, 0.f};

    const int fr = lane & 15;
    // Read-side swizzle: k-slot (lane>>4) lives at LDS slot (lane>>4)^((fr>>1)&3).
    const int swzk = (((lane >> 4) ^ ((fr >> 1) & 3)) << 3); // f16 units

    const int kt0   = z * kt_per;
    const int ktEnd = kt0 + kt_per;

#define STAGE(buf, k0)                                                                  \
    {                                                                                   \
        _Pragma("unroll")                                                               \
        for (int c = 0; c < 2; ++c) {                                                   \
            const _Float16* ga = gA0 + (size_t)(c * 64) * FEAT + (k0);                  \
            unsigned short* la = &As[buf][(c * 64 + wave * 16) * BK + lane * 8];        \
            __builtin_amdgcn_global_load_lds((const __attribute__((address_space(1))) uint32_t*)ga, \
                                             (__attribute__((address_space(3))) uint32_t*)la, 16, 0, 0); \
        }                                                                               \
        _Pragma("unroll")                                                               \
        for (int c = 0; c < 2; ++c) {                                                   \
            const _Float16* gb = gB0 + (size_t)(c * 64) * FEAT + (k0);                  \
            unsigned short* lb = &Bs[buf][(c * 64 + wave * 16) * BK + lane * 8];        \
            __builtin_amdgcn_global_load_lds((const __attribute__((address_space(1))) uint32_t*)gb, \
                                             (__attribute__((address_space(3))) uint32_t*)lb, 16, 0, 0); \
        }                                                                               \
    }

    STAGE(0, kt0 * BK);
    for (int kt = kt0; kt < ktEnd; ++kt) {
        const int cur = (kt - kt0) & 1;
        if (kt + 1 < ktEnd) {
            STAGE(cur ^ 1, (kt + 1) * BK);
            asm volatile("s_waitcnt vmcnt(4)" ::: "memory");  // cur tile's 4 done; next 4 in flight
        } else {
            asm volatile("s_waitcnt vmcnt(0)" ::: "memory");
        }
        __builtin_amdgcn_s_barrier();

        f16x8 av[4], bv[4];
        #pragma unroll
        for (int t = 0; t < 4; ++t)
            av[t] = *(const f16x8*)&As[cur][(wm + t * 16 + fr) * BK + swzk];
        #pragma unroll
        for (int t = 0; t < 4; ++t)
            bv[t] = *(const f16x8*)&Bs[cur][(wn + t * 16 + fr) * BK + swzk];
        #pragma unroll
        for (int i = 0; i < 4; ++i)
            #pragma unroll
            for (int j = 0; j < 4; ++j)
                acc[i][j] = __builtin_amdgcn_mfma_f32_16x16x32_f16(av[i], bv[j], acc[i][j], 0, 0, 0);

        __builtin_amdgcn_s_barrier();   // compute(cur) done before cur re-staged
    }
#undef STAGE

    const int crow0 = bm * BM + wm + (lane >> 4) * 4;
    const int ccol0 = bn * BN + wn + (lane & 15);
    #pragma unroll
    for (int i = 0; i < 4; ++i)
        #pragma unroll
        for (int j = 0; j < 4; ++j)
            #pragma unroll
            for (int r = 0; r < 4; ++r)
                C[(size_t)(crow0 + i * 16 + r) * NCOL + ccol0 + j * 16] = (_Float16)acc[i][j][r];
}

// ------- Kernel 3: pairwise L1+exp2, SYMMETRIC (each pair computed once) --
// R8 version verbatim (handles nparts up to 4 in the stage loop).
#define JWAVES 4
__global__ __launch_bounds__(256, 8) void k_pairwise(const _Float16* __restrict__ Mp,
                                                     int nparts,
                                                     float* __restrict__ Os) {
    __shared__ _Float16 rowl[NCOL];          // 4KB (one row, lg2e-prescaled)
    __shared__ float    part[JWAVES][2][64]; // 2KB
    const int b  = blockIdx.x;
    const int t  = threadIdx.x;
    const int w  = t >> 6;                   // wave id (o-chunk)
    const int tl = t & 63;

    const size_t PART  = (size_t)B_ROWS * NCOL;
    const size_t gbase = (size_t)b * NCOL;
    const f16x2 lg2e = { (_Float16)1.44269504f, (_Float16)1.44269504f };

    {
        f16x8 v = *(const f16x8*)(Mp + gbase + (size_t)t * 8);
        for (int z = 1; z < nparts; ++z)
            v = v + *(const f16x8*)(Mp + (size_t)z * PART + gbase + (size_t)t * 8);
        f16x2 a0 = { v[0], v[1] }, a1 = { v[2], v[3] }, a2 = { v[4], v[5] }, a3 = { v[6], v[7] };
        a0 *= lg2e; a1 *= lg2e; a2 *= lg2e; a3 *= lg2e;
        uint4 wr = { __builtin_bit_cast(unsigned, a0), __builtin_bit_cast(unsigned, a1),
                     __builtin_bit_cast(unsigned, a2), __builtin_bit_cast(unsigned, a3) };
        *(uint4*)&rowl[t * 8] = wr;
    }
    __syncthreads();

    const uint4 uaA = *(const uint4*)&rowl[tl * ND];
    const uint4 uaB = *(const uint4*)&rowl[tl * ND + 8];
    const uint4 ubA = *(const uint4*)&rowl[(tl + 64) * ND];
    const uint4 ubB = *(const uint4*)&rowl[(tl + 64) * ND + 8];
    const f16x2 ma0 = u2h(uaA.x), ma1 = u2h(uaA.y), ma2 = u2h(uaA.z), ma3 = u2h(uaA.w);
    const f16x2 ma4 = u2h(uaB.x), ma5 = u2h(uaB.y), ma6 = u2h(uaB.z), ma7 = u2h(uaB.w);
    const f16x2 mb0 = u2h(ubA.x), mb1 = u2h(ubA.y), mb2 = u2h(ubA.z), mb3 = u2h(ubA.w);
    const f16x2 mb4 = u2h(ubB.x), mb5 = u2h(ubB.y), mb6 = u2h(ubB.z), mb7 = u2h(ubB.w);

    float acc0 = 0.f, acc1 = 0.f;
    #pragma unroll 2
    for (int jj = 0; jj < 16; ++jj) {
        const int o  = w * 16 + 1 + jj;          // wave-uniform, 1..64
        const int jA = (tl + o) & 127;
        const int jB = jA ^ 64;
        const uint4 va0 = *(const uint4*)&rowl[jA * ND];
        const uint4 va1 = *(const uint4*)&rowl[jA * ND + 8];
        const uint4 vb0 = *(const uint4*)&rowl[jB * ND];
        const uint4 vb1 = *(const uint4*)&rowl[jB * ND + 8];

        float eA, eB;
        {
            f16x2 s01 = (absdiff2(ma0, u2h(va0.x)) + absdiff2(ma1, u2h(va0.y)))
                      + (absdiff2(ma2, u2h(va0.z)) + absdiff2(ma3, u2h(va0.w)));
            f16x2 s23 = (absdiff2(ma4, u2h(va1.x)) + absdiff2(ma5, u2h(va1.y)))
                      + (absdiff2(ma6, u2h(va1.z)) + absdiff2(ma7, u2h(va1.w)));
            f16x2 s = s01 + s23;
            eA = __builtin_amdgcn_exp2f(-(float)(_Float16)(s[0] + s[1]));
        }
        {
            f16x2 s01 = (absdiff2(mb0, u2h(vb0.x)) + absdiff2(mb1, u2h(vb0.y)))
                      + (absdiff2(mb2, u2h(vb0.z)) + absdiff2(mb3, u2h(vb0.w)));
            f16x2 s23 = (absdiff2(mb4, u2h(vb1.x)) + absdiff2(mb5, u2h(vb1.y)))
                      + (absdiff2(mb6, u2h(vb1.z)) + absdiff2(mb7, u2h(vb1.w)));
            f16x2 s = s01 + s23;
            eB = __builtin_amdgcn_exp2f(-(float)(_Float16)(s[0] + s[1]));
        }

        if (o < 64) {
            const int src = (tl - o) & 63;
            const float eA2 = __shfl(eA, src, 64);
            const float eB2 = __shfl(eB, src, 64);
            const bool wrap = tl < o;            // receiver-side wrap test
            acc0 += eA + (wrap ? eB2 : eA2);
            acc1 += eB + (wrap ? eA2 : eB2);
        } else {                                 // o == 64: pair {tl, tl+64}
            acc0 += eA;
            acc1 += eB;
        }
    }
    part[w][0][tl] = acc0;
    part[w][1][tl] = acc1;
    __syncthreads();
    if (t < NK) {
        const int h = t >> 6, il = t & 63;
        float s = 1.0f                            // exact diagonal term
                + (part[0][h][il] + part[1][h][il])
                + (part[2][h][il] + part[3][h][il]);
        Os[(size_t)b * NK + t] = s;
    }
}

extern "C" void kernel_launch(void* const* d_in, const int* in_sizes, int n_in,
                              void* d_out, int out_size, void* d_ws, size_t ws_size,
                              hipStream_t stream) {
    const float* x = (const float*)d_in[0];
    const float* W = (const float*)d_in[1];
    float* Os = (float*)d_out;

    char* ws = (char*)d_ws;
    _Float16* x_h = (_Float16*)ws;                                  // 8MB
    _Float16* Wt  = (_Float16*)(ws + (size_t)8  * 1024 * 1024);     // 8MB
    _Float16* Mp  = (_Float16*)(ws + (size_t)16 * 1024 * 1024);     // 8MB x nsplit

    const size_t MB = (size_t)1024 * 1024;
    int nsplit = 1;
    if      (ws_size >= 48 * MB) nsplit = 4;   // 1024 blocks = 4/CU resident
    else if (ws_size >= 32 * MB) nsplit = 2;

    k_prep<<<8192, 256, 0, stream>>>(x, W, x_h, Wt);

    dim3 gg(NCOL / BN, B_ROWS / BM, nsplit);  // 16 x 16 x nsplit
    k_gemm<<<gg, 256, 0, stream>>>(x_h, Wt, Mp, (FEAT / BK) / nsplit);

    k_pairwise<<<B_ROWS, 256, 0, stream>>>(Mp, nsplit, Os);
}

// Round 13
// 54.525 us; speedup vs baseline: 1.1916x; 1.1916x over previous
//
#include <hip/hip_runtime.h>
#include <hip/hip_bf16.h>
#include <hip/hip_fp16.h>
#include <stdint.h>

#define B_ROWS 2048
#define FEAT   2048
#define NK     128
#define ND     16
#define NCOL   2048   // NK*ND

#define BM 128
#define BN 128
#define BK 64

typedef __attribute__((ext_vector_type(4))) float    f32x4;
typedef __attribute__((ext_vector_type(8)))  _Float16 f16x8;
typedef __attribute__((ext_vector_type(4)))  _Float16 f16x4;
typedef __attribute__((ext_vector_type(2)))  _Float16 f16x2;

__device__ __forceinline__ f16x2 u2h(unsigned u) { return __builtin_bit_cast(f16x2, u); }
__device__ __forceinline__ f16x2 absdiff2(f16x2 a, f16x2 b) {
    f16x2 d = a - b;                       // v_pk_sub_f16
    unsigned u = __builtin_bit_cast(unsigned, d) & 0x7fff7fffu;  // v_and_b32 (abs both halves)
    return __builtin_bit_cast(f16x2, u);
}

// ------------- Kernel 1: fused x-convert + W-transpose/convert (f16) ------
__global__ __launch_bounds__(256) void k_prep(const float* __restrict__ x,
                                              const float* __restrict__ W,
                                              _Float16* __restrict__ x_h,
                                              _Float16* __restrict__ Wt) {
    __shared__ float tile[32][33];
    int bb = blockIdx.x;
    if (bb < 4096) {
        int i = bb * 256 + threadIdx.x;
        float4 v = ((const float4*)x)[i];
        f16x4 o = { (_Float16)v.x, (_Float16)v.y, (_Float16)v.z, (_Float16)v.w };
        *(f16x4*)&x_h[(size_t)i * 4] = o;
    } else {
        bb -= 4096;
        int tid = threadIdx.x;
        int tx = tid & 31, ty = tid >> 5;   // 32 x 8
        int n0 = (bb & 63) * 32, k0 = (bb >> 6) * 32;
        #pragma unroll
        for (int i = 0; i < 4; ++i)
            tile[ty + i * 8][tx] = W[(size_t)(k0 + ty + i * 8) * NCOL + n0 + tx];
        __syncthreads();
        #pragma unroll
        for (int i = 0; i < 4; ++i)
            Wt[(size_t)(n0 + ty + i * 8) * FEAT + k0 + tx] = (_Float16)tile[tx][ty + i * 8];
    }
}

// ---------------- Kernel 2: f16 MFMA GEMM, 2-phase dbuf + LDS swizzle -----
// R8 structure EXACTLY (BK=64, nsplit=2, counted vmcnt(8), 64KB LDS).
// Only change: bank-conflict fix. LDS[row][slot16B] holds global k-slot
// slot^(row&7): global SOURCE col is permuted at stage (LDS dest linear,
// required by global_load_lds), and the ds_read offset XORs the same term.
// Kills the 16-way conflict from the 128B row stride (6.29M conflict cyc).
__global__ __launch_bounds__(256) void k_gemm(const _Float16* __restrict__ A,
                                              const _Float16* __restrict__ Bt,
                                              _Float16* __restrict__ Cparts,
                                              int kt_per) {
    __shared__ __align__(16) unsigned short As[2][BM * BK];  // 2 x 16KB
    __shared__ __align__(16) unsigned short Bs[2][BN * BK];  // 2 x 16KB
    const int tid  = threadIdx.x;
    const int wave = tid >> 6;
    const int lane = tid & 63;
    const int bm = blockIdx.y, bn = blockIdx.x, z = blockIdx.z;
    _Float16* C = Cparts + (size_t)z * B_ROWS * NCOL;
    const int wm = (wave >> 1) * 64;
    const int wn = (wave & 1) * 64;

    const int srow  = lane >> 3;                       // 0..7 row in chunk
    const int dcol  = (lane & 7) * 8;                  // linear LDS dest col
    const int scol  = ((lane & 7) ^ (srow & 7)) * 8;   // permuted GLOBAL src col

    const int mrow_s = wave * 32 + srow;               // + r*8
    const _Float16* gA0 = A  + (size_t)(bm * BM + mrow_s) * FEAT + scol;
    const _Float16* gB0 = Bt + (size_t)(bn * BN + mrow_s) * FEAT + scol;

    f32x4 acc[4][4];
    #pragma unroll
    for (int i = 0; i < 4; ++i)
        #pragma unroll
        for (int j = 0; j < 4; ++j)
            acc[i][j] = (f32x4){0.f, 0.f, 0.f, 0.f};

    const int fr = lane & 15;
    // Read-side: k-slot g=(lane>>4) (+4 at kk=32) lives at LDS slot g^(fr&7).
    const int sk0 = (((lane >> 4) ^ (fr & 7)) << 3);   // f16 units; kk=32 -> ^32

    const int kt0   = z * kt_per;
    const int ktEnd = kt0 + kt_per;

#define STAGE(buf, k0)                                                                  \
    {                                                                                   \
        _Pragma("unroll")                                                               \
        for (int r = 0; r < 4; ++r) {                                                   \
            const _Float16* ga = gA0 + (size_t)(r * 8) * FEAT + (k0);                   \
            const _Float16* gb = gB0 + (size_t)(r * 8) * FEAT + (k0);                   \
            unsigned short* la = &As[buf][(wave * 4 + r) * 512 + srow * 64 + dcol];     \
            unsigned short* lb = &Bs[buf][(wave * 4 + r) * 512 + srow * 64 + dcol];     \
            __builtin_amdgcn_global_load_lds((const __attribute__((address_space(1))) uint32_t*)ga, \
                                             (__attribute__((address_space(3))) uint32_t*)la, 16, 0, 0); \
            __builtin_amdgcn_global_load_lds((const __attribute__((address_space(1))) uint32_t*)gb, \
                                             (__attribute__((address_space(3))) uint32_t*)lb, 16, 0, 0); \
        }                                                                               \
    }

    STAGE(0, kt0 * BK);
    for (int kt = kt0; kt < ktEnd; ++kt) {
        const int cur = (kt - kt0) & 1;
        if (kt + 1 < ktEnd) {
            STAGE(cur ^ 1, (kt + 1) * BK);
            asm volatile("s_waitcnt vmcnt(8)" ::: "memory");  // cur tile's 8 done; next in flight
        } else {
            asm volatile("s_waitcnt vmcnt(0)" ::: "memory");
        }
        __builtin_amdgcn_s_barrier();

        #pragma unroll
        for (int kk = 0; kk < BK; kk += 32) {
            const int sw = sk0 ^ kk;   // kk=32 flips slot bit 2 (^32 f16)
            f16x8 av[4], bv[4];
            #pragma unroll
            for (int t = 0; t < 4; ++t)
                av[t] = *(const f16x8*)&As[cur][(wm + t * 16 + fr) * BK + sw];
            #pragma unroll
            for (int t = 0; t < 4; ++t)
                bv[t] = *(const f16x8*)&Bs[cur][(wn + t * 16 + fr) * BK + sw];
            #pragma unroll
            for (int i = 0; i < 4; ++i)
                #pragma unroll
                for (int j = 0; j < 4; ++j)
                    acc[i][j] = __builtin_amdgcn_mfma_f32_16x16x32_f16(av[i], bv[j], acc[i][j], 0, 0, 0);
        }
        __builtin_amdgcn_s_barrier();   // compute(cur) done before cur re-staged
    }
#undef STAGE

    const int crow0 = bm * BM + wm + (lane >> 4) * 4;
    const int ccol0 = bn * BN + wn + (lane & 15);
    #pragma unroll
    for (int i = 0; i < 4; ++i)
        #pragma unroll
        for (int j = 0; j < 4; ++j)
            #pragma unroll
            for (int r = 0; r < 4; ++r)
                C[(size_t)(crow0 + i * 16 + r) * NCOL + ccol0 + j * 16] = (_Float16)acc[i][j][r];
}

// ------- Kernel 3: pairwise L1+exp2, SYMMETRIC (each pair computed once) --
// R8 version verbatim.
#define JWAVES 4
__global__ __launch_bounds__(256, 8) void k_pairwise(const _Float16* __restrict__ Mp,
                                                     int nparts,
                                                     float* __restrict__ Os) {
    __shared__ _Float16 rowl[NCOL];          // 4KB (one row, lg2e-prescaled)
    __shared__ float    part[JWAVES][2][64]; // 2KB
    const int b  = blockIdx.x;
    const int t  = threadIdx.x;
    const int w  = t >> 6;                   // wave id (o-chunk)
    const int tl = t & 63;

    const size_t PART  = (size_t)B_ROWS * NCOL;
    const size_t gbase = (size_t)b * NCOL;
    const f16x2 lg2e = { (_Float16)1.44269504f, (_Float16)1.44269504f };

    {
        f16x8 v = *(const f16x8*)(Mp + gbase + (size_t)t * 8);
        for (int z = 1; z < nparts; ++z)
            v = v + *(const f16x8*)(Mp + (size_t)z * PART + gbase + (size_t)t * 8);
        f16x2 a0 = { v[0], v[1] }, a1 = { v[2], v[3] }, a2 = { v[4], v[5] }, a3 = { v[6], v[7] };
        a0 *= lg2e; a1 *= lg2e; a2 *= lg2e; a3 *= lg2e;
        uint4 wr = { __builtin_bit_cast(unsigned, a0), __builtin_bit_cast(unsigned, a1),
                     __builtin_bit_cast(unsigned, a2), __builtin_bit_cast(unsigned, a3) };
        *(uint4*)&rowl[t * 8] = wr;
    }
    __syncthreads();

    const uint4 uaA = *(const uint4*)&rowl[tl * ND];
    const uint4 uaB = *(const uint4*)&rowl[tl * ND + 8];
    const uint4 ubA = *(const uint4*)&rowl[(tl + 64) * ND];
    const uint4 ubB = *(const uint4*)&rowl[(tl + 64) * ND + 8];
    const f16x2 ma0 = u2h(uaA.x), ma1 = u2h(uaA.y), ma2 = u2h(uaA.z), ma3 = u2h(uaA.w);
    const f16x2 ma4 = u2h(uaB.x), ma5 = u2h(uaB.y), ma6 = u2h(uaB.z), ma7 = u2h(uaB.w);
    const f16x2 mb0 = u2h(ubA.x), mb1 = u2h(ubA.y), mb2 = u2h(ubA.z), mb3 = u2h(ubA.w);
    const f16x2 mb4 = u2h(ubB.x), mb5 = u2h(ubB.y), mb6 = u2h(ubB.z), mb7 = u2h(ubB.w);

    float acc0 = 0.f, acc1 = 0.f;
    #pragma unroll 2
    for (int jj = 0; jj < 16; ++jj) {
        const int o  = w * 16 + 1 + jj;          // wave-uniform, 1..64
        const int jA = (tl + o) & 127;
        const int jB = jA ^ 64;
        const uint4 va0 = *(const uint4*)&rowl[jA * ND];
        const uint4 va1 = *(const uint4*)&rowl[jA * ND + 8];
        const uint4 vb0 = *(const uint4*)&rowl[jB * ND];
        const uint4 vb1 = *(const uint4*)&rowl[jB * ND + 8];

        float eA, eB;
        {
            f16x2 s01 = (absdiff2(ma0, u2h(va0.x)) + absdiff2(ma1, u2h(va0.y)))
                      + (absdiff2(ma2, u2h(va0.z)) + absdiff2(ma3, u2h(va0.w)));
            f16x2 s23 = (absdiff2(ma4, u2h(va1.x)) + absdiff2(ma5, u2h(va1.y)))
                      + (absdiff2(ma6, u2h(va1.z)) + absdiff2(ma7, u2h(va1.w)));
            f16x2 s = s01 + s23;
            eA = __builtin_amdgcn_exp2f(-(float)(_Float16)(s[0] + s[1]));
        }
        {
            f16x2 s01 = (absdiff2(mb0, u2h(vb0.x)) + absdiff2(mb1, u2h(vb0.y)))
                      + (absdiff2(mb2, u2h(vb0.z)) + absdiff2(mb3, u2h(vb0.w)));
            f16x2 s23 = (absdiff2(mb4, u2h(vb1.x)) + absdiff2(mb5, u2h(vb1.y)))
                      + (absdiff2(mb6, u2h(vb1.z)) + absdiff2(mb7, u2h(vb1.w)));
            f16x2 s = s01 + s23;
            eB = __builtin_amdgcn_exp2f(-(float)(_Float16)(s[0] + s[1]));
        }

        if (o < 64) {
            const int src = (tl - o) & 63;
            const float eA2 = __shfl(eA, src, 64);
            const float eB2 = __shfl(eB, src, 64);
            const bool wrap = tl < o;            // receiver-side wrap test
            acc0 += eA + (wrap ? eB2 : eA2);
            acc1 += eB + (wrap ? eA2 : eB2);
        } else {                                 // o == 64: pair {tl, tl+64}
            acc0 += eA;
            acc1 += eB;
        }
    }
    part[w][0][tl] = acc0;
    part[w][1][tl] = acc1;
    __syncthreads();
    if (t < NK) {
        const int h = t >> 6, il = t & 63;
        float s = 1.0f                            // exact diagonal term
                + (part[0][h][il] + part[1][h][il])
                + (part[2][h][il] + part[3][h][il]);
        Os[(size_t)b * NK + t] = s;
    }
}

extern "C" void kernel_launch(void* const* d_in, const int* in_sizes, int n_in,
                              void* d_out, int out_size, void* d_ws, size_t ws_size,
                              hipStream_t stream) {
    const float* x = (const float*)d_in[0];
    const float* W = (const float*)d_in[1];
    float* Os = (float*)d_out;

    char* ws = (char*)d_ws;
    _Float16* x_h = (_Float16*)ws;                                  // 8MB
    _Float16* Wt  = (_Float16*)(ws + (size_t)8  * 1024 * 1024);     // 8MB
    _Float16* Mp  = (_Float16*)(ws + (size_t)16 * 1024 * 1024);     // 8MB x nsplit

    const size_t MB = (size_t)1024 * 1024;
    const int nsplit = (ws_size >= 32 * MB) ? 2 : 1;   // 512 blocks = 2/CU, one pass

    k_prep<<<8192, 256, 0, stream>>>(x, W, x_h, Wt);

    dim3 gg(NCOL / BN, B_ROWS / BM, nsplit);  // 16 x 16 x nsplit
    k_gemm<<<gg, 256, 0, stream>>>(x_h, Wt, Mp, (FEAT / BK) / nsplit);

    k_pairwise<<<B_ROWS, 256, 0, stream>>>(Mp, nsplit, Os);
}